// Round 7
// baseline (695.888 us; speedup 1.0000x reference)
//
#include <hip/hip_runtime.h>
#include <math.h>

#define NUMR 11
#define NSTEP 64
#define BATCH 8192
#define PDIM 128
#define MC 10000
#define DT (1.0f/64.0f)
#define RDOM 5.0f
#define CAP_EPS 0.1f
#define TP (NSTEP*BATCH)        // 524288

// workspace float offsets (total 9227776 floats = 36.9 MB)
#define OFF_HIST 0              // 220 ints
#define OFF_W3EB 256            // bf16 [t][r][c][8]: o0..5, CT, pad  -> 180224 floats
#define OFF_B3E  180480         // f32 [t][r][8]: o0..5, BC, pad      -> 5632
#define OFF_BT   186112         // f32 [t][r][sa][c]                   -> 901120
#define OFF_BB   1087232        // f32 [t][r][sa]                      -> 14080
#define OFF_W2A  1101312        // bf16 A-ordered [t][4096]            -> 131072
#define OFF_WF2A 1232384        //                                      -> 131072
#define OFF_GEO  1363456        // f32 [t][p][12]                      -> 6291456
#define OFF_SM   7654912        // f32 [t][p][2] {scale, meta}         -> 1048576
#define OFF_CONTRIB 8703488     // f32 [t][p]                          -> 524288

typedef __attribute__((ext_vector_type(8))) short short8;   // 8 bf16
typedef __attribute__((ext_vector_type(4))) float f32x4;

__device__ __forceinline__ float tanh_f(float x) {
    float e = __expf(2.0f * x);
    return 1.0f - 2.0f * __builtin_amdgcn_rcpf(e + 1.0f);
}
__device__ __forceinline__ unsigned short bf16bits(float f) {
    unsigned u = __float_as_uint(f);
    return (unsigned short)((u + 0x7FFFu + ((u >> 16) & 1u)) >> 16);
}
__device__ __forceinline__ float bf16f(unsigned short s) {
    return __uint_as_float(((unsigned)s) << 16);
}

__device__ __forceinline__ void reflect3(float* p, float* g) {
    float nr = sqrtf(p[0]*p[0] + p[1]*p[1] + p[2]*p[2]);
    if (nr > RDOM) {
        float inv = 1.0f / fmaxf(nr, 1e-12f);
        float nb0 = p[0]*inv, nb1 = p[1]*inv, nb2 = p[2]*inv;
        float sc = 2.0f*RDOM - nr;
        p[0] = nb0*sc; p[1] = nb1*sc; p[2] = nb2*sc;
        #pragma unroll
        for (int j = 0; j < 3; ++j) {
            float proj = nb0*g[j] + nb1*g[3+j] + nb2*g[6+j];
            g[j]   -= 2.0f*nb0*proj;
            g[3+j] -= 2.0f*nb1*proj;
            g[6+j] -= 2.0f*nb2*proj;
        }
    }
}

// =========== K_A: fused prep (grid-partitioned; all parts independent) =====
// blocks [0,32): geom (64 lanes x 4 particles) | [32,140): hist
// [140,204): weight pack | [204,4364): tables
__launch_bounds__(256)
__global__ void k_prep(const int* __restrict__ rt0, const float* __restrict__ xt0,
                       const float* __restrict__ yt0, const float* __restrict__ dBx,
                       const float* __restrict__ dBy, const float* __restrict__ junif,
                       const float* __restrict__ sunif, const float* __restrict__ jm,
                       const float* __restrict__ cr, const float* __restrict__ cfr,
                       const float* __restrict__ mcu,
                       const float* __restrict__ W1, const float* __restrict__ b1,
                       const float* __restrict__ Wf1, const float* __restrict__ bf1,
                       const float* __restrict__ W2, const float* __restrict__ Wf2,
                       const float* __restrict__ W3, const float* __restrict__ b3,
                       const float* __restrict__ emb, const float* __restrict__ Wf3,
                       const float* __restrict__ bf3, const float* __restrict__ jump_r,
                       const float* __restrict__ jump_l,
                       float* ws, int* hist, float* out) {
    __shared__ float sbuf[244];
    __shared__ int lh[220];
    int blk = blockIdx.x, tid = threadIdx.x;

    if (blk < 32) {
        // ---------------- geom: 4 particles per lane, ILP-interleaved -----
        float* sjm = sbuf; float* scr = sbuf + 220; float* scfr = sbuf + 231;
        for (int i = tid; i < 220; i += 256) sjm[i] = jm[i];
        if (tid < 11) { scr[tid] = cr[tid]; scfr[tid] = cfr[tid]; }
        __syncthreads();
        if (tid >= 64) return;
        int p0 = blk * 64 + tid;

        int rt[4]; float xt[4][3], xin[4][3], yin[4][3], gtx[4][9], gty[4][9];
        float fun[4], run[4];
        #pragma unroll
        for (int q = 0; q < 4; ++q) {
            int p = p0 + q*2048;
            rt[q] = rt0[p];
            #pragma unroll
            for (int i = 0; i < 3; ++i) {
                xt[q][i] = xt0[p*3+i]; xin[q][i] = xt[q][i]; yin[q][i] = yt0[p*3+i];
            }
            #pragma unroll
            for (int i = 0; i < 9; ++i) {
                gtx[q][i] = (i % 4 == 0) ? 1.f : 0.f; gty[q][i] = gtx[q][i];
            }
            fun[q] = 0.f; run[q] = 1.f;
        }

        float* GEO = ws + OFF_GEO;
        float* SM  = ws + OFF_SM;
        #pragma unroll 1
        for (int t = 0; t < NSTEP; ++t) {
            #pragma unroll
            for (int q = 0; q < 4; ++q) {
                int p = p0 + q*2048;
                int base = t*BATCH + p;
                float ju = junif[base], su = sunif[base];
                float dbx0 = dBx[(size_t)base*2], dbx1 = dBx[(size_t)base*2+1];
                float dby0 = dBy[(size_t)base*3], dby1 = dBy[(size_t)base*3+1],
                      dby2 = dBy[(size_t)base*3+2];

                int r = rt[q] - 10;
                int jon = (ju < scr[r]*DT) ? 1 : 0;
                int cnt = 0;
                #pragma unroll
                for (int j = 0; j < 20; ++j) cnt += (su < sjm[r*20+j]) ? 1 : 0;
                int ind = 20 - cnt;
                int drt = (ind < 10) ? (ind+1) : -(ind-9);
                drt = jon ? drt : 0;
                int sa = (drt > 0) ? (drt-1) : ((drt < 0) ? (9-drt) : 0);
                int jf = (drt != 0) ? 1 : 0;

                float nx = fmaxf(sqrtf(xt[q][0]*xt[q][0]+xt[q][1]*xt[q][1]+xt[q][2]*xt[q][2]), 1e-12f);
                float c = fminf(1.f, fmaxf(-1.f, xt[q][2]/nx));
                float ct = sqrtf(fmaxf(0.f, 1.f - c*c));
                float st = -c;
                float rxy2 = xt[q][0]*xt[q][0] + xt[q][1]*xt[q][1];
                float cp = 1.f, sp = 0.f;
                if (rxy2 > 0.f) { float ir = 1.0f/sqrtf(rxy2); cp = xt[q][0]*ir; sp = xt[q][1]*ir; }
                float Ti[9];
                Ti[0]=cp*ct; Ti[1]=-sp; Ti[2]=cp*st;
                Ti[3]=sp*ct; Ti[4]=cp;  Ti[5]=sp*st;
                Ti[6]=-st;   Ti[7]=0.f; Ti[8]=ct;

                float sdx = 1.0f/(float)(r+10);
                float scale = run[q] * __expf(-fun[q]);

                float cx[3], cy[3];
                #pragma unroll
                for (int i = 0; i < 3; ++i) {
                    float w31 = gtx[q][i*3]*Ti[1] + gtx[q][i*3+1]*Ti[4] + gtx[q][i*3+2]*Ti[7];
                    float w32 = gtx[q][i*3]*Ti[2] + gtx[q][i*3+1]*Ti[5] + gtx[q][i*3+2]*Ti[8];
                    cx[i] = sdx * (w31*dbx1 - w32*dbx0);
                    cy[i] = gty[q][i*3]*dby0 + gty[q][i*3+1]*dby1 + gty[q][i*3+2]*dby2;
                }
                float* gp = GEO + (size_t)base*12;
                float4 v0 = {xin[q][0], xin[q][1], xin[q][2], yin[q][0]};
                float4 v1 = {yin[q][1], yin[q][2], cx[0], cx[1]};
                float4 v2 = {cx[2], cy[0], cy[1], cy[2]};
                *(float4*)(gp)     = v0;
                *(float4*)(gp + 4) = v1;
                *(float4*)(gp + 8) = v2;
                float2 smv = {scale, __int_as_float(r | (sa<<8) | (jf<<16))};
                *(float2*)(SM + (size_t)base*2) = smv;

                fun[q] += scfr[r]*DT;

                float dX0 = sdx*dbx0, dX1 = sdx*dbx1;
                float s0 = __sinf(dX0), cc0 = __cosf(dX0);
                float s1 = __sinf(dX1), cc1 = __cosf(dX1);
                float cart0 = cc0*cc1 - 1.0f, cart1 = cc0*s1, cart2 = -s0;
                float dX3[3];
                #pragma unroll
                for (int i = 0; i < 3; ++i)
                    dX3[i] = Ti[i*3]*cart0 + Ti[i*3+1]*cart1 + Ti[i*3+2]*cart2;
                #pragma unroll
                for (int i = 0; i < 3; ++i) xt[q][i] += dX3[i];
                #pragma unroll
                for (int i = 0; i < 3; ++i)
                    xin[q][i] += gtx[q][i*3]*dX3[0] + gtx[q][i*3+1]*dX3[1] + gtx[q][i*3+2]*dX3[2];
                #pragma unroll
                for (int i = 0; i < 3; ++i)
                    yin[q][i] += gty[q][i*3]*dby0 + gty[q][i*3+1]*dby1 + gty[q][i*3+2]*dby2;
                rt[q] += drt; rt[q] = (rt[q] < 10) ? 10 : ((rt[q] > 20) ? 20 : rt[q]);
                reflect3(xin[q], gtx[q]);
                reflect3(yin[q], gty[q]);
                float d0 = xin[q][0]-yin[q][0], d1 = xin[q][1]-yin[q][1], d2 = xin[q][2]-yin[q][2];
                if (sqrtf(d0*d0 + d1*d1 + d2*d2) < CAP_EPS) run[q] = 0.f;
            }
        }
        #pragma unroll
        for (int q = 0; q < 4; ++q) {
            int p = p0 + q*2048;
            float d0 = xin[q][0]-yin[q][0], d1 = xin[q][1]-yin[q][1], d2 = xin[q][2]-yin[q][2];
            float u0v = __expf(-(d0*d0 + d1*d1 + d2*d2));
            out[BATCH + p] = run[q] * u0v * __expf(-fun[q]);
        }

    } else if (blk < 140) {
        // ---------------- hist ----------------
        for (int i = tid; i < 220; i += 256) lh[i] = 0;
        __syncthreads();
        int hb = blk - 32;
        #pragma unroll
        for (int j = 0; j < 4; ++j) {
            int i = hb*1024 + j*256 + tid;
            if (i < MC*NUMR) {
                int r = i % NUMR;
                float u = mcu[i];
                int cnt = 0;
                #pragma unroll
                for (int k = 0; k < 20; ++k) cnt += (u < jm[r*20+k]) ? 1 : 0;
                int ind = 20 - cnt;
                int s = (ind < 10) ? (ind+1) : -(ind-9);
                int sa = (s > 0) ? (s-1) : (10 + (-s-1));
                atomicAdd(&lh[r*20+sa], 1);
            }
        }
        __syncthreads();
        if (tid < 220 && lh[tid]) atomicAdd(&hist[tid], lh[tid]);

    } else if (blk < 204) {
        // ---------------- weight pack: W2/Wf2 -> bf16 MFMA-A-lane order ----
        int t = blk - 140;
        unsigned short* W2A  = (unsigned short*)(ws + OFF_W2A)  + t*4096;
        unsigned short* WF2A = (unsigned short*)(ws + OFF_WF2A) + t*4096;
        for (int i = tid; i < 4096; i += 256) {
            int j = i & 7, L = (i >> 3) & 63, ktct = i >> 9;
            int ct = ktct >> 1, kt = ktct & 1;
            int c = ct*16 + (L & 15);
            int k = kt*32 + (L >> 4)*8 + j;
            W2A[i]  = bf16bits(W2[t*4096 + k*64 + c]);
            WF2A[i] = bf16bits(Wf2[t*4096 + k*64 + c]);
        }

    } else {
        // ---------------- tables (W3E slots 0-5 bf16, B3E, BT, BB) --------
        int idx = blk - 204;
        int t = idx / 65, kk = idx % 65;
        bool brow = (kk == 64);
        const float* w3row = brow ? (b3 + t*768) : (W3 + (t*64+kk)*768);
        const float* wfrow = brow ? (bf3 + t*128) : (Wf3 + (t*64+kk)*128);
        unsigned short* W3EB = (unsigned short*)(ws + OFF_W3EB);
        for (int q = tid; q < 286; q += 256) {
            if (q < 66) {
                int o = q / 11, r = q % 11;
                const float* e = emb + (t*11+r)*128;
                float a0 = 0.f, a1 = 0.f;
                #pragma unroll 4
                for (int p = 0; p < 128; p += 2) {
                    a0 = fmaf(e[p],   w3row[p*6+o],     a0);
                    a1 = fmaf(e[p+1], w3row[(p+1)*6+o], a1);
                }
                float acc = a0 + a1;
                if (brow) ws[OFF_B3E + (t*11+r)*8 + o] = acc;
                else      W3EB[(size_t)((t*11+r)*64 + kk)*8 + o] = bf16bits(acc);
            } else {
                int qq = q - 66;
                int sa = qq / 11, r = qq % 11;
                float a0 = 0.f, a1 = 0.f;
                #pragma unroll 4
                for (int p = 0; p < 128; p += 2) {
                    a0 = fmaf(wfrow[p],   jump_r[r*128+p]   * jump_l[sa*128+p],   a0);
                    a1 = fmaf(wfrow[p+1], jump_r[r*128+p+1] * jump_l[sa*128+p+1], a1);
                }
                float acc = a0 + a1;
                if (brow) ws[OFF_BB + (t*11+r)*20 + sa] = acc;
                else      ws[OFF_BT + ((size_t)(t*11+r)*20 + sa)*64 + kk] = acc;
            }
        }
    }
}

// =========== K_B: CT/BC from MC histogram (CT = sum_sa histn*BT) ==========
__global__ void k_fold(const int* __restrict__ hist, const float* __restrict__ cr,
                       float* ws) {
    int t = blockIdx.x, tid = threadIdx.x;
    unsigned short* W3EB = (unsigned short*)(ws + OFF_W3EB);
    for (int i = tid; i < 715; i += 256) {
        if (i < 704) {
            int r = i >> 6, c = i & 63;
            float crn = cr[r] * (1.0f/(float)MC);
            const float* btp = ws + OFF_BT + (size_t)(t*11+r)*20*64 + c;
            float acc = 0.f;
            #pragma unroll
            for (int sa = 0; sa < 20; ++sa)
                acc += (float)hist[r*20+sa] * btp[sa*64];
            W3EB[(size_t)((t*11+r)*64 + c)*8 + 6] = bf16bits(acc * crn);
        } else {
            int r = i - 704;
            float crn = cr[r] * (1.0f/(float)MC);
            float acc = 0.f;
            #pragma unroll
            for (int sa = 0; sa < 20; ++sa)
                acc += (float)hist[r*20+sa] * ws[OFF_BB + (t*11+r)*20 + sa];
            ws[OFF_B3E + (t*11+r)*8 + 6] = acc * crn;
        }
    }
}

// =========== K5: MFMA MLP, W2 staged in LDS (A-lane order) ================
__launch_bounds__(256, 6)
__global__ void k_mlp(const float* __restrict__ ws,
                      const float* __restrict__ W1, const float* __restrict__ b1,
                      const float* __restrict__ Wf1, const float* __restrict__ bf1,
                      const float* __restrict__ b2, const float* __restrict__ bf2,
                      float* __restrict__ contrib) {
    __shared__ unsigned short sW2[4096], sWf2[4096];
    int tid = threadIdx.x;
    int t = blockIdx.x & 63;
    {
        const unsigned* g2  = (const unsigned*)((const unsigned short*)(ws + OFF_W2A)  + t*4096);
        const unsigned* g2f = (const unsigned*)((const unsigned short*)(ws + OFF_WF2A) + t*4096);
        unsigned* s2  = (unsigned*)sW2;
        unsigned* s2f = (unsigned*)sWf2;
        #pragma unroll
        for (int i = 0; i < 8; ++i) {
            s2[i*256 + tid]  = g2[i*256 + tid];
            s2f[i*256 + tid] = g2f[i*256 + tid];
        }
    }
    __syncthreads();
    int L = tid & 63, l15 = L & 15, q4 = L >> 4;
    int pbase = (blockIdx.x >> 6) * 256 + (tid >> 6) * 64;

    float4 bh4[4], bf4[4];
    #pragma unroll
    for (int ct = 0; ct < 4; ++ct) {
        bh4[ct] = *(const float4*)(b2  + t*64 + ct*16 + q4*4);
        bf4[ct] = *(const float4*)(bf2 + t*64 + ct*16 + q4*4);
    }
    const float* GEO = ws + OFF_GEO;
    const float* SM  = ws + OFF_SM;
    const float* W1t  = W1  + t*384;
    const float* Wf1t = Wf1 + t*384;
    const float* b1t  = b1  + t*64;
    const float* bf1t = bf1 + t*64;
    const unsigned short* W3EBt = (const unsigned short*)(ws + OFF_W3EB);

    #pragma unroll 1
    for (int g = 0; g < 4; ++g) {
        int p = pbase + g*16 + l15;
        int base = t*BATCH + p;
        float2 sm = *(const float2*)(SM + (size_t)base*2);
        float scale = sm.x;
        if (__ballot(scale != 0.f) == 0ULL) {
            if (q4 == 0) contrib[base] = 0.f;
            continue;
        }
        int meta = __float_as_int(sm.y);
        float4 ga = *(const float4*)(GEO + (size_t)base*12);
        float4 gb = *(const float4*)(GEO + (size_t)base*12 + 4);
        float4 gc = *(const float4*)(GEO + (size_t)base*12 + 8);
        float inp[6]  = {ga.x, ga.y, ga.z, ga.w, gb.x, gb.y};
        float coef[6] = {gb.z, gb.w, gc.x, gc.y, gc.z, gc.w};
        int r = meta & 255, sa = (meta >> 8) & 255;
        bool jump = ((meta >> 16) & 1) != 0;

        // L1 -> B-fragments (B[k=q4*8+j][n=l15])
        short8 bh[2], bfr[2];
        #pragma unroll
        for (int kt = 0; kt < 2; ++kt) {
            int kb = kt*32 + q4*8;
            float av[8], fv[8];
            #pragma unroll
            for (int j = 0; j < 8; ++j) { av[j] = b1t[kb+j]; fv[j] = bf1t[kb+j]; }
            #pragma unroll
            for (int i = 0; i < 6; ++i) {
                float x = inp[i];
                #pragma unroll
                for (int j = 0; j < 8; ++j) {
                    av[j] = fmaf(x, W1t[i*64 + kb + j],  av[j]);
                    fv[j] = fmaf(x, Wf1t[i*64 + kb + j], fv[j]);
                }
            }
            short8 vh, vf;
            #pragma unroll
            for (int j = 0; j < 8; ++j) {
                vh[j] = (short)bf16bits(tanh_f(av[j]));
                vf[j] = (short)bf16bits(tanh_f(fv[j]));
            }
            bh[kt] = vh; bfr[kt] = vf;
        }

        const unsigned short* W3E8 = W3EBt + (size_t)((t*11 + r)*64)*8;
        const float* btp = ws + OFF_BT + ((size_t)(t*11 + r)*20 + sa)*64;
        float pdp = 0.f;
        #pragma unroll
        for (int ct = 0; ct < 4; ++ct) {
            short8 a0 = *(const short8*)(sW2  + ((ct*2 + 0)*64 + L)*8);
            short8 a1 = *(const short8*)(sW2  + ((ct*2 + 1)*64 + L)*8);
            short8 c0 = *(const short8*)(sWf2 + ((ct*2 + 0)*64 + L)*8);
            short8 c1 = *(const short8*)(sWf2 + ((ct*2 + 1)*64 + L)*8);
            f32x4 acc = {0.f, 0.f, 0.f, 0.f};
            acc = __builtin_amdgcn_mfma_f32_16x16x32_bf16(a0, bh[0], acc, 0, 0, 0);
            acc = __builtin_amdgcn_mfma_f32_16x16x32_bf16(a1, bh[1], acc, 0, 0, 0);
            f32x4 accf = {0.f, 0.f, 0.f, 0.f};
            accf = __builtin_amdgcn_mfma_f32_16x16x32_bf16(c0, bfr[0], accf, 0, 0, 0);
            accf = __builtin_amdgcn_mfma_f32_16x16x32_bf16(c1, bfr[1], accf, 0, 0, 0);
            const float* bhp = (const float*)&bh4[ct];
            const float* bfp = (const float*)&bf4[ct];
            #pragma unroll
            for (int reg = 0; reg < 4; ++reg) {
                float h2 = tanh_f(acc[reg]  + bhp[reg]);
                float f2 = tanh_f(accf[reg] + bfp[reg]);
                int c = ct*16 + q4*4 + reg;
                short8 wv = *(const short8*)(W3E8 + c*8);
                float s = bf16f((unsigned short)wv[0])*coef[0]
                        + bf16f((unsigned short)wv[1])*coef[1]
                        + bf16f((unsigned short)wv[2])*coef[2]
                        + bf16f((unsigned short)wv[3])*coef[3]
                        + bf16f((unsigned short)wv[4])*coef[4]
                        + bf16f((unsigned short)wv[5])*coef[5];
                pdp = fmaf(h2, s, pdp);
                pdp = fmaf(f2, -DT*bf16f((unsigned short)wv[6]), pdp);
                if (jump) pdp = fmaf(f2, btp[c], pdp);
            }
        }
        pdp += __shfl_xor(pdp, 16, 64);
        pdp += __shfl_xor(pdp, 32, 64);

        const float* B3E8 = ws + OFF_B3E + (t*11 + r)*8;
        float4 ba  = *(const float4*)(B3E8);
        float4 bbv = *(const float4*)(B3E8 + 4);
        float dpart = pdp
            + ba.x*coef[0] + ba.y*coef[1] + ba.z*coef[2]
            + ba.w*coef[3] + bbv.x*coef[4] + bbv.y*coef[5]
            - DT*bbv.z;
        if (jump) dpart += ws[OFF_BB + (t*11 + r)*20 + sa];
        if (q4 == 0) contrib[base] = scale * dpart;
    }
}

// =========== K6: reduce over t ============================================
__global__ void k_reduce(const float* __restrict__ contrib, const float* __restrict__ u,
                         float* out) {
    __shared__ float red[256];
    int tid = threadIdx.x;
    int pi = tid & 31, tc = tid >> 5;
    int p = blockIdx.x * 32 + pi;
    float a = 0.f;
    #pragma unroll
    for (int j = 0; j < 8; ++j) a += contrib[(tc*8 + j)*BATCH + p];
    red[tid] = a;
    __syncthreads();
    if (tid < 32) {
        float s = u[0];
        #pragma unroll
        for (int c = 0; c < 8; ++c) s += red[c*32 + pi];
        out[p] = s;
    }
}

extern "C" void kernel_launch(void* const* d_in, const int* in_sizes, int n_in,
                              void* d_out, int out_size, void* d_ws, size_t ws_size,
                              hipStream_t stream) {
    const float* u      = (const float*)d_in[0];
    const float* jump_r = (const float*)d_in[1];
    const float* jump_l = (const float*)d_in[2];
    const float* W1  = (const float*)d_in[3];
    const float* b1  = (const float*)d_in[4];
    const float* W2  = (const float*)d_in[5];
    const float* b2  = (const float*)d_in[6];
    const float* W3  = (const float*)d_in[7];
    const float* b3  = (const float*)d_in[8];
    const float* emb = (const float*)d_in[9];
    const float* Wf1 = (const float*)d_in[10];
    const float* bf1 = (const float*)d_in[11];
    const float* Wf2 = (const float*)d_in[12];
    const float* bf2 = (const float*)d_in[13];
    const float* Wf3 = (const float*)d_in[14];
    const float* bf3 = (const float*)d_in[15];
    const int*   rt0 = (const int*)d_in[16];
    const float* xt0 = (const float*)d_in[17];
    const float* yt0 = (const float*)d_in[18];
    const float* dBx = (const float*)d_in[19];
    const float* dBy = (const float*)d_in[20];
    const float* junif = (const float*)d_in[21];
    const float* sunif = (const float*)d_in[22];
    const float* mcu = (const float*)d_in[23];
    const float* jm  = (const float*)d_in[24];
    const float* cr  = (const float*)d_in[25];
    const float* cfr = (const float*)d_in[26];
    float* ws  = (float*)d_ws;
    float* out = (float*)d_out;

    hipMemsetAsync(ws + OFF_HIST, 0, 220*sizeof(int), stream);
    k_prep<<<4364, 256, 0, stream>>>(rt0, xt0, yt0, dBx, dBy, junif, sunif,
                                     jm, cr, cfr, mcu,
                                     W1, b1, Wf1, bf1, W2, Wf2,
                                     W3, b3, emb, Wf3, bf3, jump_r, jump_l,
                                     ws, (int*)(ws + OFF_HIST), out);
    k_fold<<<64, 256, 0, stream>>>((const int*)(ws + OFF_HIST), cr, ws);
    k_mlp<<<2048, 256, 0, stream>>>(ws, W1, b1, Wf1, bf1, b2, bf2,
                                    ws + OFF_CONTRIB);
    k_reduce<<<256, 256, 0, stream>>>(ws + OFF_CONTRIB, u, out);
}

// Round 8
// 415.451 us; speedup vs baseline: 1.6750x; 1.6750x over previous
//
#include <hip/hip_runtime.h>
#include <math.h>

#define NUMR 11
#define NSTEP 64
#define BATCH 8192
#define PDIM 128
#define MC 10000
#define DT (1.0f/64.0f)
#define RDOM 5.0f
#define CAP_EPS 0.1f
#define TP (NSTEP*BATCH)        // 524288

// workspace float offsets (total 9227776 floats = 36.9 MB)
#define OFF_HIST 0              // 220 ints
#define OFF_W3EB 256            // bf16 [t][r][c][8]: o0..5, CT, pad  -> 180224 floats
#define OFF_B3E  180480         // f32 [t][r][8]: o0..5, BC, pad      -> 5632
#define OFF_BT   186112         // f32 [t][r][sa][c]                   -> 901120
#define OFF_BB   1087232        // f32 [t][r][sa]                      -> 14080
#define OFF_W2A  1101312        // bf16 A-ordered [t][4096]            -> 131072
#define OFF_WF2A 1232384        //                                      -> 131072
#define OFF_GEO  1363456        // f32 [t][p][12]                      -> 6291456
#define OFF_SM   7654912        // f32 [t][p][2] {scale, meta}         -> 1048576
#define OFF_CONTRIB 8703488     // f32 [t][p]                          -> 524288

typedef __attribute__((ext_vector_type(8))) short short8;   // 8 bf16
typedef __attribute__((ext_vector_type(4))) float f32x4;

__device__ __forceinline__ float tanh_f(float x) {
    float e = __expf(2.0f * x);
    return 1.0f - 2.0f * __builtin_amdgcn_rcpf(e + 1.0f);
}
__device__ __forceinline__ unsigned short bf16bits(float f) {
    unsigned u = __float_as_uint(f);
    return (unsigned short)((u + 0x7FFFu + ((u >> 16) & 1u)) >> 16);
}
__device__ __forceinline__ float bf16f(unsigned short s) {
    return __uint_as_float(((unsigned)s) << 16);
}

__device__ __forceinline__ void reflect3(float* p, float* g) {
    float nr = sqrtf(p[0]*p[0] + p[1]*p[1] + p[2]*p[2]);
    if (nr > RDOM) {
        float inv = 1.0f / fmaxf(nr, 1e-12f);   // exact div: trajectory-sensitive
        float nb0 = p[0]*inv, nb1 = p[1]*inv, nb2 = p[2]*inv;
        float sc = 2.0f*RDOM - nr;
        p[0] = nb0*sc; p[1] = nb1*sc; p[2] = nb2*sc;
        #pragma unroll
        for (int j = 0; j < 3; ++j) {
            float proj = nb0*g[j] + nb1*g[3+j] + nb2*g[6+j];
            g[j]   -= 2.0f*nb0*proj;
            g[3+j] -= 2.0f*nb1*proj;
            g[6+j] -= 2.0f*nb2*proj;
        }
    }
}

// =========== K_G: trajectory geometry (own dispatch for profiling) ========
__launch_bounds__(64)
__global__ void k_geom(const int* __restrict__ rt0, const float* __restrict__ xt0,
                       const float* __restrict__ yt0, const float* __restrict__ dBx,
                       const float* __restrict__ dBy, const float* __restrict__ junif,
                       const float* __restrict__ sunif, const float* __restrict__ jm,
                       const float* __restrict__ cr, const float* __restrict__ cfr,
                       float* ws, float* out) {
    __shared__ float sjm[220], scr[11], smul[11];
    int tid = threadIdx.x;
    for (int i = tid; i < 220; i += 64) sjm[i] = jm[i];
    if (tid < 11) { scr[tid] = cr[tid]; smul[tid] = __expf(-cfr[tid]*DT); }
    __syncthreads();
    int p = blockIdx.x * 64 + tid;

    int rt = rt0[p];
    float xt[3], xin[3], yin[3], gtx[9], gty[9];
    #pragma unroll
    for (int i = 0; i < 3; ++i) { xt[i] = xt0[p*3+i]; xin[i] = xt[i]; yin[i] = yt0[p*3+i]; }
    #pragma unroll
    for (int i = 0; i < 9; ++i) { gtx[i] = (i % 4 == 0) ? 1.f : 0.f; gty[i] = gtx[i]; }
    float ef = 1.f, run = 1.f;   // ef = exp(-fun) as running product (LUT)

    float ju = junif[p], su = sunif[p];
    float dbx0 = dBx[(size_t)p*2], dbx1 = dBx[(size_t)p*2+1];
    float dby0 = dBy[(size_t)p*3], dby1 = dBy[(size_t)p*3+1], dby2 = dBy[(size_t)p*3+2];

    float* GEO = ws + OFF_GEO;
    float* SM  = ws + OFF_SM;
    #pragma unroll 1
    for (int t = 0; t < NSTEP; ++t) {
        float nju=0.f,nsu=0.f,ndbx0=0.f,ndbx1=0.f,ndby0=0.f,ndby1=0.f,ndby2=0.f;
        if (t < NSTEP-1) {
            int nb = (t+1)*BATCH + p;
            nju = junif[nb]; nsu = sunif[nb];
            ndbx0 = dBx[(size_t)nb*2]; ndbx1 = dBx[(size_t)nb*2+1];
            ndby0 = dBy[(size_t)nb*3]; ndby1 = dBy[(size_t)nb*3+1]; ndby2 = dBy[(size_t)nb*3+2];
        }
        int base = t*BATCH + p;
        int r = rt - 10;
        int jon = (ju < scr[r]*DT) ? 1 : 0;
        int cnt = 0;
        #pragma unroll
        for (int j = 0; j < 20; ++j) cnt += (su < sjm[r*20+j]) ? 1 : 0;
        int ind = 20 - cnt;
        int drt = (ind < 10) ? (ind+1) : -(ind-9);
        drt = jon ? drt : 0;
        int sa = (drt > 0) ? (drt-1) : ((drt < 0) ? (9-drt) : 0);
        int jf = (drt != 0) ? 1 : 0;

        float nx = fmaxf(sqrtf(xt[0]*xt[0]+xt[1]*xt[1]+xt[2]*xt[2]), 1e-12f);
        float c = fminf(1.f, fmaxf(-1.f, xt[2]/nx));
        float ct = sqrtf(fmaxf(0.f, 1.f - c*c));
        float st = -c;
        float rxy2 = xt[0]*xt[0] + xt[1]*xt[1];
        float cp = 1.f, sp = 0.f;
        if (rxy2 > 0.f) { float ir = 1.0f/sqrtf(rxy2); cp = xt[0]*ir; sp = xt[1]*ir; }
        float Ti[9];
        Ti[0]=cp*ct; Ti[1]=-sp; Ti[2]=cp*st;
        Ti[3]=sp*ct; Ti[4]=cp;  Ti[5]=sp*st;
        Ti[6]=-st;   Ti[7]=0.f; Ti[8]=ct;

        float sdx = 1.0f/(float)(r+10);
        float scale = run * ef;

        float cx[3], cy[3];
        #pragma unroll
        for (int i = 0; i < 3; ++i) {
            float w31 = gtx[i*3]*Ti[1] + gtx[i*3+1]*Ti[4] + gtx[i*3+2]*Ti[7];
            float w32 = gtx[i*3]*Ti[2] + gtx[i*3+1]*Ti[5] + gtx[i*3+2]*Ti[8];
            cx[i] = sdx * (w31*dbx1 - w32*dbx0);
            cy[i] = gty[i*3]*dby0 + gty[i*3+1]*dby1 + gty[i*3+2]*dby2;
        }
        float* gp = GEO + (size_t)base*12;
        float4 v0 = {xin[0], xin[1], xin[2], yin[0]};
        float4 v1 = {yin[1], yin[2], cx[0], cx[1]};
        float4 v2 = {cx[2], cy[0], cy[1], cy[2]};
        *(float4*)(gp)     = v0;
        *(float4*)(gp + 4) = v1;
        *(float4*)(gp + 8) = v2;
        float2 smv = {scale, __int_as_float(r | (sa<<8) | (jf<<16))};
        *(float2*)(SM + (size_t)base*2) = smv;

        ef *= smul[r];

        // Taylor sin/cos: |dX| <= ~0.075, err ~8e-9 (below ulp noise)
        float dX0 = sdx*dbx0, dX1 = sdx*dbx1;
        float x2 = dX0*dX0, y2 = dX1*dX1;
        float s0 = dX0*(1.f - x2*(1.f/6.f));
        float cc0 = 1.f - x2*0.5f + x2*x2*(1.f/24.f);
        float s1 = dX1*(1.f - y2*(1.f/6.f));
        float cc1 = 1.f - y2*0.5f + y2*y2*(1.f/24.f);
        float cart0 = cc0*cc1 - 1.0f, cart1 = cc0*s1, cart2 = -s0;
        float dX3[3];
        #pragma unroll
        for (int i = 0; i < 3; ++i)
            dX3[i] = Ti[i*3]*cart0 + Ti[i*3+1]*cart1 + Ti[i*3+2]*cart2;
        #pragma unroll
        for (int i = 0; i < 3; ++i) xt[i] += dX3[i];
        #pragma unroll
        for (int i = 0; i < 3; ++i)
            xin[i] += gtx[i*3]*dX3[0] + gtx[i*3+1]*dX3[1] + gtx[i*3+2]*dX3[2];
        #pragma unroll
        for (int i = 0; i < 3; ++i)
            yin[i] += gty[i*3]*dby0 + gty[i*3+1]*dby1 + gty[i*3+2]*dby2;
        rt += drt; rt = (rt < 10) ? 10 : ((rt > 20) ? 20 : rt);
        reflect3(xin, gtx);
        reflect3(yin, gty);
        float d0 = xin[0]-yin[0], d1 = xin[1]-yin[1], d2 = xin[2]-yin[2];
        if (sqrtf(d0*d0 + d1*d1 + d2*d2) < CAP_EPS) run = 0.f;

        ju = nju; su = nsu; dbx0 = ndbx0; dbx1 = ndbx1;
        dby0 = ndby0; dby1 = ndby1; dby2 = ndby2;
    }
    float d0 = xin[0]-yin[0], d1 = xin[1]-yin[1], d2 = xin[2]-yin[2];
    float u0v = __expf(-(d0*d0 + d1*d1 + d2*d2));
    out[BATCH + p] = run * u0v * ef;
}

// =========== K_A: hist | weight pack | tables (grid-partitioned) ==========
// [0,108): hist | [108,172): pack | [172,4332): tables
__launch_bounds__(256)
__global__ void k_prep2(const float* __restrict__ jm, const float* __restrict__ mcu,
                        const float* __restrict__ W2, const float* __restrict__ Wf2,
                        const float* __restrict__ W3, const float* __restrict__ b3,
                        const float* __restrict__ emb, const float* __restrict__ Wf3,
                        const float* __restrict__ bf3, const float* __restrict__ jump_r,
                        const float* __restrict__ jump_l,
                        float* ws, int* hist) {
    __shared__ int lh[220];
    int blk = blockIdx.x, tid = threadIdx.x;

    if (blk < 108) {
        for (int i = tid; i < 220; i += 256) lh[i] = 0;
        __syncthreads();
        #pragma unroll
        for (int j = 0; j < 4; ++j) {
            int i = blk*1024 + j*256 + tid;
            if (i < MC*NUMR) {
                int r = i % NUMR;
                float u = mcu[i];
                int cnt = 0;
                #pragma unroll
                for (int k = 0; k < 20; ++k) cnt += (u < jm[r*20+k]) ? 1 : 0;
                int ind = 20 - cnt;
                int s = (ind < 10) ? (ind+1) : -(ind-9);
                int sa = (s > 0) ? (s-1) : (10 + (-s-1));
                atomicAdd(&lh[r*20+sa], 1);
            }
        }
        __syncthreads();
        if (tid < 220 && lh[tid]) atomicAdd(&hist[tid], lh[tid]);

    } else if (blk < 172) {
        int t = blk - 108;
        unsigned short* W2A  = (unsigned short*)(ws + OFF_W2A)  + t*4096;
        unsigned short* WF2A = (unsigned short*)(ws + OFF_WF2A) + t*4096;
        for (int i = tid; i < 4096; i += 256) {
            int j = i & 7, L = (i >> 3) & 63, ktct = i >> 9;
            int ct = ktct >> 1, kt = ktct & 1;
            int c = ct*16 + (L & 15);
            int k = kt*32 + (L >> 4)*8 + j;
            W2A[i]  = bf16bits(W2[t*4096 + k*64 + c]);
            WF2A[i] = bf16bits(Wf2[t*4096 + k*64 + c]);
        }

    } else {
        int idx = blk - 172;
        int t = idx / 65, kk = idx % 65;
        bool brow = (kk == 64);
        const float* w3row = brow ? (b3 + t*768) : (W3 + (t*64+kk)*768);
        const float* wfrow = brow ? (bf3 + t*128) : (Wf3 + (t*64+kk)*128);
        unsigned short* W3EB = (unsigned short*)(ws + OFF_W3EB);
        for (int q = tid; q < 286; q += 256) {
            if (q < 66) {
                int o = q / 11, r = q % 11;
                const float* e = emb + (t*11+r)*128;
                float a0 = 0.f, a1 = 0.f;
                #pragma unroll 4
                for (int p = 0; p < 128; p += 2) {
                    a0 = fmaf(e[p],   w3row[p*6+o],     a0);
                    a1 = fmaf(e[p+1], w3row[(p+1)*6+o], a1);
                }
                float acc = a0 + a1;
                if (brow) ws[OFF_B3E + (t*11+r)*8 + o] = acc;
                else      W3EB[(size_t)((t*11+r)*64 + kk)*8 + o] = bf16bits(acc);
            } else {
                int qq = q - 66;
                int sa = qq / 11, r = qq % 11;
                float a0 = 0.f, a1 = 0.f;
                #pragma unroll 4
                for (int p = 0; p < 128; p += 2) {
                    a0 = fmaf(wfrow[p],   jump_r[r*128+p]   * jump_l[sa*128+p],   a0);
                    a1 = fmaf(wfrow[p+1], jump_r[r*128+p+1] * jump_l[sa*128+p+1], a1);
                }
                float acc = a0 + a1;
                if (brow) ws[OFF_BB + (t*11+r)*20 + sa] = acc;
                else      ws[OFF_BT + ((size_t)(t*11+r)*20 + sa)*64 + kk] = acc;
            }
        }
    }
}

// =========== K_B: CT/BC from MC histogram =================================
__global__ void k_fold(const int* __restrict__ hist, const float* __restrict__ cr,
                       float* ws) {
    int t = blockIdx.x, tid = threadIdx.x;
    unsigned short* W3EB = (unsigned short*)(ws + OFF_W3EB);
    for (int i = tid; i < 715; i += 256) {
        if (i < 704) {
            int r = i >> 6, c = i & 63;
            float crn = cr[r] * (1.0f/(float)MC);
            const float* btp = ws + OFF_BT + (size_t)(t*11+r)*20*64 + c;
            float acc = 0.f;
            #pragma unroll
            for (int sa = 0; sa < 20; ++sa)
                acc += (float)hist[r*20+sa] * btp[sa*64];
            W3EB[(size_t)((t*11+r)*64 + c)*8 + 6] = bf16bits(acc * crn);
        } else {
            int r = i - 704;
            float crn = cr[r] * (1.0f/(float)MC);
            float acc = 0.f;
            #pragma unroll
            for (int sa = 0; sa < 20; ++sa)
                acc += (float)hist[r*20+sa] * ws[OFF_BB + (t*11+r)*20 + sa];
            ws[OFF_B3E + (t*11+r)*8 + 6] = acc * crn;
        }
    }
}

// =========== K5: MFMA MLP; W2 + all r-tables staged in LDS ================
__launch_bounds__(256, 3)
__global__ void k_mlp(const float* __restrict__ ws,
                      const float* __restrict__ W1, const float* __restrict__ b1,
                      const float* __restrict__ Wf1, const float* __restrict__ bf1,
                      const float* __restrict__ b2, const float* __restrict__ bf2,
                      float* __restrict__ contrib) {
    __shared__ unsigned short sW2[4096], sWf2[4096];
    __shared__ unsigned short sW3E[11*520];   // r-stride 520 (pad 8) kills bank aliasing
    __shared__ float sB3E[11*12];
    __shared__ float sBB[220];
    int tid = threadIdx.x;
    int t = blockIdx.x & 63;
    {
        const unsigned* g2  = (const unsigned*)((const unsigned short*)(ws + OFF_W2A)  + t*4096);
        const unsigned* g2f = (const unsigned*)((const unsigned short*)(ws + OFF_WF2A) + t*4096);
        unsigned* s2  = (unsigned*)sW2;
        unsigned* s2f = (unsigned*)sWf2;
        #pragma unroll
        for (int i = 0; i < 8; ++i) {
            s2[i*256 + tid]  = g2[i*256 + tid];
            s2f[i*256 + tid] = g2f[i*256 + tid];
        }
        const unsigned* g3 = (const unsigned*)((const unsigned short*)(ws + OFF_W3EB) + (size_t)t*5632);
        unsigned* s3 = (unsigned*)sW3E;
        for (int i = tid; i < 2816; i += 256) {
            int r = i >> 8, off = i & 255;
            s3[r*260 + off] = g3[i];
        }
        if (tid < 88) {
            int r = tid >> 3, o = tid & 7;
            sB3E[r*12 + o] = ws[OFF_B3E + t*88 + tid];
        }
        if (tid < 220) sBB[tid] = ws[OFF_BB + t*220 + tid];
    }
    __syncthreads();
    int L = tid & 63, l15 = L & 15, q4 = L >> 4;
    int pbase = (blockIdx.x >> 6) * 256 + (tid >> 6) * 64;

    float4 bh4[4], bf4[4];
    #pragma unroll
    for (int ct = 0; ct < 4; ++ct) {
        bh4[ct] = *(const float4*)(b2  + t*64 + ct*16 + q4*4);
        bf4[ct] = *(const float4*)(bf2 + t*64 + ct*16 + q4*4);
    }
    const float* GEO = ws + OFF_GEO;
    const float* SM  = ws + OFF_SM;
    const float* W1t  = W1  + t*384;
    const float* Wf1t = Wf1 + t*384;
    const float* b1t  = b1  + t*64;
    const float* bf1t = bf1 + t*64;

    // prefetch g=0
    int base_n = t*BATCH + pbase + l15;
    float2 sm_n = *(const float2*)(SM + (size_t)base_n*2);
    float4 ga_n = *(const float4*)(GEO + (size_t)base_n*12);
    float4 gb_n = *(const float4*)(GEO + (size_t)base_n*12 + 4);
    float4 gc_n = *(const float4*)(GEO + (size_t)base_n*12 + 8);

    #pragma unroll 1
    for (int g = 0; g < 4; ++g) {
        int base = base_n;
        float2 sm = sm_n;
        float4 ga = ga_n, gb = gb_n, gc = gc_n;
        if (g < 3) {
            base_n = t*BATCH + pbase + (g+1)*16 + l15;
            sm_n = *(const float2*)(SM + (size_t)base_n*2);
            ga_n = *(const float4*)(GEO + (size_t)base_n*12);
            gb_n = *(const float4*)(GEO + (size_t)base_n*12 + 4);
            gc_n = *(const float4*)(GEO + (size_t)base_n*12 + 8);
        }
        float scale = sm.x;
        if (__ballot(scale != 0.f) == 0ULL) {
            if (q4 == 0) contrib[base] = 0.f;
            continue;
        }
        int meta = __float_as_int(sm.y);
        float inp[6]  = {ga.x, ga.y, ga.z, ga.w, gb.x, gb.y};
        float coef[6] = {gb.z, gb.w, gc.x, gc.y, gc.z, gc.w};
        int r = meta & 255, sa = (meta >> 8) & 255;
        bool jump = ((meta >> 16) & 1) != 0;

        // L1 -> B-fragments (B[k=q4*8+j][n=l15])
        short8 bh[2], bfr[2];
        #pragma unroll
        for (int kt = 0; kt < 2; ++kt) {
            int kb = kt*32 + q4*8;
            float av[8], fv[8];
            #pragma unroll
            for (int j = 0; j < 8; ++j) { av[j] = b1t[kb+j]; fv[j] = bf1t[kb+j]; }
            #pragma unroll
            for (int i = 0; i < 6; ++i) {
                float x = inp[i];
                #pragma unroll
                for (int j = 0; j < 8; ++j) {
                    av[j] = fmaf(x, W1t[i*64 + kb + j],  av[j]);
                    fv[j] = fmaf(x, Wf1t[i*64 + kb + j], fv[j]);
                }
            }
            short8 vh, vf;
            #pragma unroll
            for (int j = 0; j < 8; ++j) {
                vh[j] = (short)bf16bits(tanh_f(av[j]));
                vf[j] = (short)bf16bits(tanh_f(fv[j]));
            }
            bh[kt] = vh; bfr[kt] = vf;
        }

        const unsigned short* W3E8 = sW3E + r*520;
        const float* btp = ws + OFF_BT + ((size_t)(t*11 + r)*20 + sa)*64;
        float pdp = 0.f;
        #pragma unroll
        for (int ct = 0; ct < 4; ++ct) {
            short8 a0 = *(const short8*)(sW2  + ((ct*2 + 0)*64 + L)*8);
            short8 a1 = *(const short8*)(sW2  + ((ct*2 + 1)*64 + L)*8);
            short8 c0 = *(const short8*)(sWf2 + ((ct*2 + 0)*64 + L)*8);
            short8 c1 = *(const short8*)(sWf2 + ((ct*2 + 1)*64 + L)*8);
            f32x4 acc = {0.f, 0.f, 0.f, 0.f};
            acc = __builtin_amdgcn_mfma_f32_16x16x32_bf16(a0, bh[0], acc, 0, 0, 0);
            acc = __builtin_amdgcn_mfma_f32_16x16x32_bf16(a1, bh[1], acc, 0, 0, 0);
            f32x4 accf = {0.f, 0.f, 0.f, 0.f};
            accf = __builtin_amdgcn_mfma_f32_16x16x32_bf16(c0, bfr[0], accf, 0, 0, 0);
            accf = __builtin_amdgcn_mfma_f32_16x16x32_bf16(c1, bfr[1], accf, 0, 0, 0);
            const float* bhp = (const float*)&bh4[ct];
            const float* bfp = (const float*)&bf4[ct];
            #pragma unroll
            for (int reg = 0; reg < 4; ++reg) {
                float h2 = tanh_f(acc[reg]  + bhp[reg]);
                float f2 = tanh_f(accf[reg] + bfp[reg]);
                int c = ct*16 + q4*4 + reg;
                short8 wv = *(const short8*)(W3E8 + c*8);
                float s = bf16f((unsigned short)wv[0])*coef[0]
                        + bf16f((unsigned short)wv[1])*coef[1]
                        + bf16f((unsigned short)wv[2])*coef[2]
                        + bf16f((unsigned short)wv[3])*coef[3]
                        + bf16f((unsigned short)wv[4])*coef[4]
                        + bf16f((unsigned short)wv[5])*coef[5];
                pdp = fmaf(h2, s, pdp);
                pdp = fmaf(f2, -DT*bf16f((unsigned short)wv[6]), pdp);
                if (jump) pdp = fmaf(f2, btp[c], pdp);
            }
        }
        pdp += __shfl_xor(pdp, 16, 64);
        pdp += __shfl_xor(pdp, 32, 64);

        const float* B3E8 = sB3E + r*12;
        float4 ba  = *(const float4*)(B3E8);
        float4 bbv = *(const float4*)(B3E8 + 4);
        float dpart = pdp
            + ba.x*coef[0] + ba.y*coef[1] + ba.z*coef[2]
            + ba.w*coef[3] + bbv.x*coef[4] + bbv.y*coef[5]
            - DT*bbv.z;
        if (jump) dpart += sBB[r*20 + sa];
        if (q4 == 0) contrib[base] = scale * dpart;
    }
}

// =========== K6: reduce over t ============================================
__global__ void k_reduce(const float* __restrict__ contrib, const float* __restrict__ u,
                         float* out) {
    __shared__ float red[256];
    int tid = threadIdx.x;
    int pi = tid & 31, tc = tid >> 5;
    int p = blockIdx.x * 32 + pi;
    float a = 0.f;
    #pragma unroll
    for (int j = 0; j < 8; ++j) a += contrib[(tc*8 + j)*BATCH + p];
    red[tid] = a;
    __syncthreads();
    if (tid < 32) {
        float s = u[0];
        #pragma unroll
        for (int c = 0; c < 8; ++c) s += red[c*32 + pi];
        out[p] = s;
    }
}

extern "C" void kernel_launch(void* const* d_in, const int* in_sizes, int n_in,
                              void* d_out, int out_size, void* d_ws, size_t ws_size,
                              hipStream_t stream) {
    const float* u      = (const float*)d_in[0];
    const float* jump_r = (const float*)d_in[1];
    const float* jump_l = (const float*)d_in[2];
    const float* W1  = (const float*)d_in[3];
    const float* b1  = (const float*)d_in[4];
    const float* W2  = (const float*)d_in[5];
    const float* b2  = (const float*)d_in[6];
    const float* W3  = (const float*)d_in[7];
    const float* b3  = (const float*)d_in[8];
    const float* emb = (const float*)d_in[9];
    const float* Wf1 = (const float*)d_in[10];
    const float* bf1 = (const float*)d_in[11];
    const float* Wf2 = (const float*)d_in[12];
    const float* bf2 = (const float*)d_in[13];
    const float* Wf3 = (const float*)d_in[14];
    const float* bf3 = (const float*)d_in[15];
    const int*   rt0 = (const int*)d_in[16];
    const float* xt0 = (const float*)d_in[17];
    const float* yt0 = (const float*)d_in[18];
    const float* dBx = (const float*)d_in[19];
    const float* dBy = (const float*)d_in[20];
    const float* junif = (const float*)d_in[21];
    const float* sunif = (const float*)d_in[22];
    const float* mcu = (const float*)d_in[23];
    const float* jm  = (const float*)d_in[24];
    const float* cr  = (const float*)d_in[25];
    const float* cfr = (const float*)d_in[26];
    float* ws  = (float*)d_ws;
    float* out = (float*)d_out;

    hipMemsetAsync(ws + OFF_HIST, 0, 220*sizeof(int), stream);
    k_geom<<<128, 64, 0, stream>>>(rt0, xt0, yt0, dBx, dBy, junif, sunif,
                                   jm, cr, cfr, ws, out);
    k_prep2<<<4332, 256, 0, stream>>>(jm, mcu, W2, Wf2, W3, b3, emb, Wf3, bf3,
                                      jump_r, jump_l, ws, (int*)(ws + OFF_HIST));
    k_fold<<<64, 256, 0, stream>>>((const int*)(ws + OFF_HIST), cr, ws);
    k_mlp<<<2048, 256, 0, stream>>>(ws, W1, b1, Wf1, bf1, b2, bf2,
                                    ws + OFF_CONTRIB);
    k_reduce<<<256, 256, 0, stream>>>(ws + OFF_CONTRIB, u, out);
}

// Round 9
// 342.085 us; speedup vs baseline: 2.0343x; 1.2145x over previous
//
#include <hip/hip_runtime.h>
#include <math.h>

#define NUMR 11
#define NSTEP 64
#define BATCH 8192
#define PDIM 128
#define MC 10000
#define DT (1.0f/64.0f)
#define RDOM 5.0f
#define CAP_EPS 0.1f
#define TP (NSTEP*BATCH)        // 524288

// workspace float offsets (total 9227776 floats = 36.9 MB)
#define OFF_HIST 0              // 220 ints
#define OFF_W3EB 256            // bf16 [t][r][c][8]: o0..5, CT, pad  -> 180224 floats
#define OFF_B3E  180480         // f32 [t][r][8]: o0..5, BC, pad      -> 5632
#define OFF_BT   186112         // f32 [t][r][sa][c]                   -> 901120
#define OFF_BB   1087232        // f32 [t][r][sa]                      -> 14080
#define OFF_W2A  1101312        // bf16 A-ordered [t][4096]            -> 131072
#define OFF_WF2A 1232384        //                                      -> 131072
#define OFF_GEO  1363456        // f32 [t][p][12]                      -> 6291456
#define OFF_SM   7654912        // f32 [t][p][2] {scale, meta}         -> 1048576
#define OFF_CONTRIB 8703488     // f32 [t][p]                          -> 524288

typedef __attribute__((ext_vector_type(8))) short short8;   // 8 bf16
typedef __attribute__((ext_vector_type(4))) float f32x4;

__device__ __forceinline__ float tanh_f(float x) {
    float e = __expf(2.0f * x);
    return 1.0f - 2.0f * __builtin_amdgcn_rcpf(e + 1.0f);
}
__device__ __forceinline__ unsigned short bf16bits(float f) {
    unsigned u = __float_as_uint(f);
    return (unsigned short)((u + 0x7FFFu + ((u >> 16) & 1u)) >> 16);
}
__device__ __forceinline__ float bf16f(unsigned short s) {
    return __uint_as_float(((unsigned)s) << 16);
}

__device__ __forceinline__ void reflect3(float* p, float* g) {
    float nr = sqrtf(p[0]*p[0] + p[1]*p[1] + p[2]*p[2]);
    if (nr > RDOM) {
        float inv = 1.0f / fmaxf(nr, 1e-12f);   // exact div: trajectory-sensitive
        float nb0 = p[0]*inv, nb1 = p[1]*inv, nb2 = p[2]*inv;
        float sc = 2.0f*RDOM - nr;
        p[0] = nb0*sc; p[1] = nb1*sc; p[2] = nb2*sc;
        #pragma unroll
        for (int j = 0; j < 3; ++j) {
            float proj = nb0*g[j] + nb1*g[3+j] + nb2*g[6+j];
            g[j]   -= 2.0f*nb0*proj;
            g[3+j] -= 2.0f*nb1*proj;
            g[6+j] -= 2.0f*nb2*proj;
        }
    }
}

// =========== K_A: fused prep ==============================================
// [0,128): geom (64 working lanes) | [128,236): hist | [236,300): pack
// [300,4460): tables.  Geom (latency-bound chain) overlaps with the
// throughput-bound table/hist/pack blocks on the same CUs.
__launch_bounds__(256)
__global__ void k_prep(const int* __restrict__ rt0, const float* __restrict__ xt0,
                       const float* __restrict__ yt0, const float* __restrict__ dBx,
                       const float* __restrict__ dBy, const float* __restrict__ junif,
                       const float* __restrict__ sunif, const float* __restrict__ jm,
                       const float* __restrict__ cr, const float* __restrict__ cfr,
                       const float* __restrict__ mcu,
                       const float* __restrict__ W2, const float* __restrict__ Wf2,
                       const float* __restrict__ W3, const float* __restrict__ b3,
                       const float* __restrict__ emb, const float* __restrict__ Wf3,
                       const float* __restrict__ bf3, const float* __restrict__ jump_r,
                       const float* __restrict__ jump_l,
                       float* ws, int* hist, float* out) {
    __shared__ float sbuf[242];
    __shared__ int lh[220];
    int blk = blockIdx.x, tid = threadIdx.x;

    if (blk < 128) {
        // ---------------- geom: 1 particle/thread, 64 working lanes -------
        float* sjm = sbuf; float* scr = sbuf + 220; float* smul = sbuf + 231;
        for (int i = tid; i < 220; i += 256) sjm[i] = jm[i];
        if (tid < 11) { scr[tid] = cr[tid]; smul[tid] = __expf(-cfr[tid]*DT); }
        __syncthreads();
        if (tid >= 64) return;
        int p = blk * 64 + tid;

        int rt = rt0[p];
        float xt[3], xin[3], yin[3], gtx[9], gty[9];
        #pragma unroll
        for (int i = 0; i < 3; ++i) { xt[i] = xt0[p*3+i]; xin[i] = xt[i]; yin[i] = yt0[p*3+i]; }
        #pragma unroll
        for (int i = 0; i < 9; ++i) { gtx[i] = (i % 4 == 0) ? 1.f : 0.f; gty[i] = gtx[i]; }
        float ef = 1.f, run = 1.f;   // ef = exp(-fun) as running LUT product

        float ju = junif[p], su = sunif[p];
        float dbx0 = dBx[(size_t)p*2], dbx1 = dBx[(size_t)p*2+1];
        float dby0 = dBy[(size_t)p*3], dby1 = dBy[(size_t)p*3+1], dby2 = dBy[(size_t)p*3+2];

        float* GEO = ws + OFF_GEO;
        float* SM  = ws + OFF_SM;
        #pragma unroll 1
        for (int t = 0; t < NSTEP; ++t) {
            float nju=0.f,nsu=0.f,ndbx0=0.f,ndbx1=0.f,ndby0=0.f,ndby1=0.f,ndby2=0.f;
            if (t < NSTEP-1) {
                int nb = (t+1)*BATCH + p;
                nju = junif[nb]; nsu = sunif[nb];
                ndbx0 = dBx[(size_t)nb*2]; ndbx1 = dBx[(size_t)nb*2+1];
                ndby0 = dBy[(size_t)nb*3]; ndby1 = dBy[(size_t)nb*3+1]; ndby2 = dBy[(size_t)nb*3+2];
            }
            int base = t*BATCH + p;
            int r = rt - 10;
            int jon = (ju < scr[r]*DT) ? 1 : 0;
            int cnt = 0;
            #pragma unroll
            for (int j = 0; j < 20; ++j) cnt += (su < sjm[r*20+j]) ? 1 : 0;
            int ind = 20 - cnt;
            int drt = (ind < 10) ? (ind+1) : -(ind-9);
            drt = jon ? drt : 0;
            int sa = (drt > 0) ? (drt-1) : ((drt < 0) ? (9-drt) : 0);
            int jf = (drt != 0) ? 1 : 0;

            float nx = fmaxf(sqrtf(xt[0]*xt[0]+xt[1]*xt[1]+xt[2]*xt[2]), 1e-12f);
            float c = fminf(1.f, fmaxf(-1.f, xt[2]/nx));
            float ct = sqrtf(fmaxf(0.f, 1.f - c*c));
            float st = -c;
            float rxy2 = xt[0]*xt[0] + xt[1]*xt[1];
            float cp = 1.f, sp = 0.f;
            if (rxy2 > 0.f) { float ir = 1.0f/sqrtf(rxy2); cp = xt[0]*ir; sp = xt[1]*ir; }
            float Ti[9];
            Ti[0]=cp*ct; Ti[1]=-sp; Ti[2]=cp*st;
            Ti[3]=sp*ct; Ti[4]=cp;  Ti[5]=sp*st;
            Ti[6]=-st;   Ti[7]=0.f; Ti[8]=ct;

            float sdx = 1.0f/(float)(r+10);
            float scale = run * ef;

            float cx[3], cy[3];
            #pragma unroll
            for (int i = 0; i < 3; ++i) {
                float w31 = gtx[i*3]*Ti[1] + gtx[i*3+1]*Ti[4] + gtx[i*3+2]*Ti[7];
                float w32 = gtx[i*3]*Ti[2] + gtx[i*3+1]*Ti[5] + gtx[i*3+2]*Ti[8];
                cx[i] = sdx * (w31*dbx1 - w32*dbx0);
                cy[i] = gty[i*3]*dby0 + gty[i*3+1]*dby1 + gty[i*3+2]*dby2;
            }
            float* gp = GEO + (size_t)base*12;
            float4 v0 = {xin[0], xin[1], xin[2], yin[0]};
            float4 v1 = {yin[1], yin[2], cx[0], cx[1]};
            float4 v2 = {cx[2], cy[0], cy[1], cy[2]};
            *(float4*)(gp)     = v0;
            *(float4*)(gp + 4) = v1;
            *(float4*)(gp + 8) = v2;
            float2 smv = {scale, __int_as_float(r | (sa<<8) | (jf<<16))};
            *(float2*)(SM + (size_t)base*2) = smv;

            ef *= smul[r];

            // Taylor sin/cos: |dX| <= ~0.075, err ~8e-9
            float dX0 = sdx*dbx0, dX1 = sdx*dbx1;
            float x2 = dX0*dX0, y2 = dX1*dX1;
            float s0 = dX0*(1.f - x2*(1.f/6.f));
            float cc0 = 1.f - x2*0.5f + x2*x2*(1.f/24.f);
            float s1 = dX1*(1.f - y2*(1.f/6.f));
            float cc1 = 1.f - y2*0.5f + y2*y2*(1.f/24.f);
            float cart0 = cc0*cc1 - 1.0f, cart1 = cc0*s1, cart2 = -s0;
            float dX3[3];
            #pragma unroll
            for (int i = 0; i < 3; ++i)
                dX3[i] = Ti[i*3]*cart0 + Ti[i*3+1]*cart1 + Ti[i*3+2]*cart2;
            #pragma unroll
            for (int i = 0; i < 3; ++i) xt[i] += dX3[i];
            #pragma unroll
            for (int i = 0; i < 3; ++i)
                xin[i] += gtx[i*3]*dX3[0] + gtx[i*3+1]*dX3[1] + gtx[i*3+2]*dX3[2];
            #pragma unroll
            for (int i = 0; i < 3; ++i)
                yin[i] += gty[i*3]*dby0 + gty[i*3+1]*dby1 + gty[i*3+2]*dby2;
            rt += drt; rt = (rt < 10) ? 10 : ((rt > 20) ? 20 : rt);
            reflect3(xin, gtx);
            reflect3(yin, gty);
            float d0 = xin[0]-yin[0], d1 = xin[1]-yin[1], d2 = xin[2]-yin[2];
            if (sqrtf(d0*d0 + d1*d1 + d2*d2) < CAP_EPS) run = 0.f;

            ju = nju; su = nsu; dbx0 = ndbx0; dbx1 = ndbx1;
            dby0 = ndby0; dby1 = ndby1; dby2 = ndby2;
        }
        float d0 = xin[0]-yin[0], d1 = xin[1]-yin[1], d2 = xin[2]-yin[2];
        float u0v = __expf(-(d0*d0 + d1*d1 + d2*d2));
        out[BATCH + p] = run * u0v * ef;

    } else if (blk < 236) {
        // ---------------- hist ----------------
        for (int i = tid; i < 220; i += 256) lh[i] = 0;
        __syncthreads();
        int hb = blk - 128;
        #pragma unroll
        for (int j = 0; j < 4; ++j) {
            int i = hb*1024 + j*256 + tid;
            if (i < MC*NUMR) {
                int r = i % NUMR;
                float u = mcu[i];
                int cnt = 0;
                #pragma unroll
                for (int k = 0; k < 20; ++k) cnt += (u < jm[r*20+k]) ? 1 : 0;
                int ind = 20 - cnt;
                int s = (ind < 10) ? (ind+1) : -(ind-9);
                int sa = (s > 0) ? (s-1) : (10 + (-s-1));
                atomicAdd(&lh[r*20+sa], 1);
            }
        }
        __syncthreads();
        if (tid < 220 && lh[tid]) atomicAdd(&hist[tid], lh[tid]);

    } else if (blk < 300) {
        // ---------------- pack W2/Wf2 -> bf16 MFMA-A-lane order -----------
        int t = blk - 236;
        unsigned short* W2A  = (unsigned short*)(ws + OFF_W2A)  + t*4096;
        unsigned short* WF2A = (unsigned short*)(ws + OFF_WF2A) + t*4096;
        for (int i = tid; i < 4096; i += 256) {
            int j = i & 7, L = (i >> 3) & 63, ktct = i >> 9;
            int ct = ktct >> 1, kt = ktct & 1;
            int c = ct*16 + (L & 15);
            int k = kt*32 + (L >> 4)*8 + j;
            W2A[i]  = bf16bits(W2[t*4096 + k*64 + c]);
            WF2A[i] = bf16bits(Wf2[t*4096 + k*64 + c]);
        }

    } else {
        // ---------------- tables (W3E slots 0-5 bf16, B3E, BT, BB) --------
        int idx = blk - 300;
        int t = idx / 65, kk = idx % 65;
        bool brow = (kk == 64);
        const float* w3row = brow ? (b3 + t*768) : (W3 + (t*64+kk)*768);
        const float* wfrow = brow ? (bf3 + t*128) : (Wf3 + (t*64+kk)*128);
        unsigned short* W3EB = (unsigned short*)(ws + OFF_W3EB);
        for (int q = tid; q < 286; q += 256) {
            if (q < 66) {
                int o = q / 11, r = q % 11;
                const float* e = emb + (t*11+r)*128;
                float a0 = 0.f, a1 = 0.f;
                #pragma unroll 4
                for (int p = 0; p < 128; p += 2) {
                    a0 = fmaf(e[p],   w3row[p*6+o],     a0);
                    a1 = fmaf(e[p+1], w3row[(p+1)*6+o], a1);
                }
                float acc = a0 + a1;
                if (brow) ws[OFF_B3E + (t*11+r)*8 + o] = acc;
                else      W3EB[(size_t)((t*11+r)*64 + kk)*8 + o] = bf16bits(acc);
            } else {
                int qq = q - 66;
                int sa = qq / 11, r = qq % 11;
                float a0 = 0.f, a1 = 0.f;
                #pragma unroll 4
                for (int p = 0; p < 128; p += 2) {
                    a0 = fmaf(wfrow[p],   jump_r[r*128+p]   * jump_l[sa*128+p],   a0);
                    a1 = fmaf(wfrow[p+1], jump_r[r*128+p+1] * jump_l[sa*128+p+1], a1);
                }
                float acc = a0 + a1;
                if (brow) ws[OFF_BB + (t*11+r)*20 + sa] = acc;
                else      ws[OFF_BT + ((size_t)(t*11+r)*20 + sa)*64 + kk] = acc;
            }
        }
    }
}

// =========== K_B: CT/BC from MC histogram =================================
__global__ void k_fold(const int* __restrict__ hist, const float* __restrict__ cr,
                       float* ws) {
    int t = blockIdx.x, tid = threadIdx.x;
    unsigned short* W3EB = (unsigned short*)(ws + OFF_W3EB);
    for (int i = tid; i < 715; i += 256) {
        if (i < 704) {
            int r = i >> 6, c = i & 63;
            float crn = cr[r] * (1.0f/(float)MC);
            const float* btp = ws + OFF_BT + (size_t)(t*11+r)*20*64 + c;
            float acc = 0.f;
            #pragma unroll
            for (int sa = 0; sa < 20; ++sa)
                acc += (float)hist[r*20+sa] * btp[sa*64];
            W3EB[(size_t)((t*11+r)*64 + c)*8 + 6] = bf16bits(acc * crn);
        } else {
            int r = i - 704;
            float crn = cr[r] * (1.0f/(float)MC);
            float acc = 0.f;
            #pragma unroll
            for (int sa = 0; sa < 20; ++sa)
                acc += (float)hist[r*20+sa] * ws[OFF_BB + (t*11+r)*20 + sa];
            ws[OFF_B3E + (t*11+r)*8 + 6] = acc * crn;
        }
    }
}

// =========== K5: MFMA MLP; W2 + r-tables in LDS; 4 blocks/CU ==============
__launch_bounds__(256, 4)
__global__ void k_mlp(const float* __restrict__ ws,
                      const float* __restrict__ W1, const float* __restrict__ b1,
                      const float* __restrict__ Wf1, const float* __restrict__ bf1,
                      const float* __restrict__ b2, const float* __restrict__ bf2,
                      float* __restrict__ contrib) {
    __shared__ unsigned short sW2[4096], sWf2[4096];
    __shared__ unsigned short sW3E[11*520];   // r-stride 520 (pad 8)
    __shared__ float sB3E[11*12];
    __shared__ float sBB[220];
    int tid = threadIdx.x;
    int t = blockIdx.x & 63;
    {
        const unsigned* g2  = (const unsigned*)((const unsigned short*)(ws + OFF_W2A)  + t*4096);
        const unsigned* g2f = (const unsigned*)((const unsigned short*)(ws + OFF_WF2A) + t*4096);
        unsigned* s2  = (unsigned*)sW2;
        unsigned* s2f = (unsigned*)sWf2;
        #pragma unroll
        for (int i = 0; i < 8; ++i) {
            s2[i*256 + tid]  = g2[i*256 + tid];
            s2f[i*256 + tid] = g2f[i*256 + tid];
        }
        const unsigned* g3 = (const unsigned*)((const unsigned short*)(ws + OFF_W3EB) + (size_t)t*5632);
        unsigned* s3 = (unsigned*)sW3E;
        for (int i = tid; i < 2816; i += 256) {
            int r = i >> 8, off = i & 255;
            s3[r*260 + off] = g3[i];
        }
        if (tid < 88) {
            int r = tid >> 3, o = tid & 7;
            sB3E[r*12 + o] = ws[OFF_B3E + t*88 + tid];
        }
        if (tid < 220) sBB[tid] = ws[OFF_BB + t*220 + tid];
    }
    __syncthreads();
    int L = tid & 63, l15 = L & 15, q4 = L >> 4;
    int pbase = (blockIdx.x >> 6) * 256 + (tid >> 6) * 64;

    float4 bh4[4], bf4[4];
    #pragma unroll
    for (int ct = 0; ct < 4; ++ct) {
        bh4[ct] = *(const float4*)(b2  + t*64 + ct*16 + q4*4);
        bf4[ct] = *(const float4*)(bf2 + t*64 + ct*16 + q4*4);
    }
    const float* GEO = ws + OFF_GEO;
    const float* SM  = ws + OFF_SM;
    const float* W1t  = W1  + t*384;
    const float* Wf1t = Wf1 + t*384;
    const float* b1t  = b1  + t*64;
    const float* bf1t = bf1 + t*64;

    // prefetch g=0
    int base_n = t*BATCH + pbase + l15;
    float2 sm_n = *(const float2*)(SM + (size_t)base_n*2);
    float4 ga_n = *(const float4*)(GEO + (size_t)base_n*12);
    float4 gb_n = *(const float4*)(GEO + (size_t)base_n*12 + 4);
    float4 gc_n = *(const float4*)(GEO + (size_t)base_n*12 + 8);

    #pragma unroll 1
    for (int g = 0; g < 4; ++g) {
        int base = base_n;
        float2 sm = sm_n;
        float4 ga = ga_n, gb = gb_n, gc = gc_n;
        if (g < 3) {
            base_n = t*BATCH + pbase + (g+1)*16 + l15;
            sm_n = *(const float2*)(SM + (size_t)base_n*2);
            ga_n = *(const float4*)(GEO + (size_t)base_n*12);
            gb_n = *(const float4*)(GEO + (size_t)base_n*12 + 4);
            gc_n = *(const float4*)(GEO + (size_t)base_n*12 + 8);
        }
        float scale = sm.x;
        if (__ballot(scale != 0.f) == 0ULL) {
            if (q4 == 0) contrib[base] = 0.f;
            continue;
        }
        int meta = __float_as_int(sm.y);
        float inp[6]  = {ga.x, ga.y, ga.z, ga.w, gb.x, gb.y};
        float coef[6] = {gb.z, gb.w, gc.x, gc.y, gc.z, gc.w};
        int r = meta & 255, sa = (meta >> 8) & 255;
        bool jump = ((meta >> 16) & 1) != 0;

        // L1 -> B-fragments (B[k=q4*8+j][n=l15])
        short8 bh[2], bfr[2];
        #pragma unroll
        for (int kt = 0; kt < 2; ++kt) {
            int kb = kt*32 + q4*8;
            float av[8], fv[8];
            #pragma unroll
            for (int j = 0; j < 8; ++j) { av[j] = b1t[kb+j]; fv[j] = bf1t[kb+j]; }
            #pragma unroll
            for (int i = 0; i < 6; ++i) {
                float x = inp[i];
                #pragma unroll
                for (int j = 0; j < 8; ++j) {
                    av[j] = fmaf(x, W1t[i*64 + kb + j],  av[j]);
                    fv[j] = fmaf(x, Wf1t[i*64 + kb + j], fv[j]);
                }
            }
            short8 vh, vf;
            #pragma unroll
            for (int j = 0; j < 8; ++j) {
                vh[j] = (short)bf16bits(tanh_f(av[j]));
                vf[j] = (short)bf16bits(tanh_f(fv[j]));
            }
            bh[kt] = vh; bfr[kt] = vf;
        }

        const unsigned short* W3E8 = sW3E + r*520;
        const float* btp = ws + OFF_BT + ((size_t)(t*11 + r)*20 + sa)*64;
        float pdp = 0.f;
        #pragma unroll
        for (int ct = 0; ct < 4; ++ct) {
            short8 a0 = *(const short8*)(sW2  + ((ct*2 + 0)*64 + L)*8);
            short8 a1 = *(const short8*)(sW2  + ((ct*2 + 1)*64 + L)*8);
            short8 c0 = *(const short8*)(sWf2 + ((ct*2 + 0)*64 + L)*8);
            short8 c1 = *(const short8*)(sWf2 + ((ct*2 + 1)*64 + L)*8);
            f32x4 acc = {0.f, 0.f, 0.f, 0.f};
            acc = __builtin_amdgcn_mfma_f32_16x16x32_bf16(a0, bh[0], acc, 0, 0, 0);
            acc = __builtin_amdgcn_mfma_f32_16x16x32_bf16(a1, bh[1], acc, 0, 0, 0);
            f32x4 accf = {0.f, 0.f, 0.f, 0.f};
            accf = __builtin_amdgcn_mfma_f32_16x16x32_bf16(c0, bfr[0], accf, 0, 0, 0);
            accf = __builtin_amdgcn_mfma_f32_16x16x32_bf16(c1, bfr[1], accf, 0, 0, 0);
            const float* bhp = (const float*)&bh4[ct];
            const float* bfp = (const float*)&bf4[ct];
            #pragma unroll
            for (int reg = 0; reg < 4; ++reg) {
                float h2 = tanh_f(acc[reg]  + bhp[reg]);
                float f2 = tanh_f(accf[reg] + bfp[reg]);
                int c = ct*16 + q4*4 + reg;
                short8 wv = *(const short8*)(W3E8 + c*8);
                float s = bf16f((unsigned short)wv[0])*coef[0]
                        + bf16f((unsigned short)wv[1])*coef[1]
                        + bf16f((unsigned short)wv[2])*coef[2]
                        + bf16f((unsigned short)wv[3])*coef[3]
                        + bf16f((unsigned short)wv[4])*coef[4]
                        + bf16f((unsigned short)wv[5])*coef[5];
                pdp = fmaf(h2, s, pdp);
                pdp = fmaf(f2, -DT*bf16f((unsigned short)wv[6]), pdp);
                if (jump) pdp = fmaf(f2, btp[c], pdp);
            }
        }
        pdp += __shfl_xor(pdp, 16, 64);
        pdp += __shfl_xor(pdp, 32, 64);

        const float* B3E8 = sB3E + r*12;
        float4 ba  = *(const float4*)(B3E8);
        float4 bbv = *(const float4*)(B3E8 + 4);
        float dpart = pdp
            + ba.x*coef[0] + ba.y*coef[1] + ba.z*coef[2]
            + ba.w*coef[3] + bbv.x*coef[4] + bbv.y*coef[5]
            - DT*bbv.z;
        if (jump) dpart += sBB[r*20 + sa];
        if (q4 == 0) contrib[base] = scale * dpart;
    }
}

// =========== K6: reduce over t ============================================
__global__ void k_reduce(const float* __restrict__ contrib, const float* __restrict__ u,
                         float* out) {
    __shared__ float red[256];
    int tid = threadIdx.x;
    int pi = tid & 31, tc = tid >> 5;
    int p = blockIdx.x * 32 + pi;
    float a = 0.f;
    #pragma unroll
    for (int j = 0; j < 8; ++j) a += contrib[(tc*8 + j)*BATCH + p];
    red[tid] = a;
    __syncthreads();
    if (tid < 32) {
        float s = u[0];
        #pragma unroll
        for (int c = 0; c < 8; ++c) s += red[c*32 + pi];
        out[p] = s;
    }
}

extern "C" void kernel_launch(void* const* d_in, const int* in_sizes, int n_in,
                              void* d_out, int out_size, void* d_ws, size_t ws_size,
                              hipStream_t stream) {
    const float* u      = (const float*)d_in[0];
    const float* jump_r = (const float*)d_in[1];
    const float* jump_l = (const float*)d_in[2];
    const float* W1  = (const float*)d_in[3];
    const float* b1  = (const float*)d_in[4];
    const float* W2  = (const float*)d_in[5];
    const float* b2  = (const float*)d_in[6];
    const float* W3  = (const float*)d_in[7];
    const float* b3  = (const float*)d_in[8];
    const float* emb = (const float*)d_in[9];
    const float* Wf1 = (const float*)d_in[10];
    const float* bf1 = (const float*)d_in[11];
    const float* Wf2 = (const float*)d_in[12];
    const float* bf2 = (const float*)d_in[13];
    const float* Wf3 = (const float*)d_in[14];
    const float* bf3 = (const float*)d_in[15];
    const int*   rt0 = (const int*)d_in[16];
    const float* xt0 = (const float*)d_in[17];
    const float* yt0 = (const float*)d_in[18];
    const float* dBx = (const float*)d_in[19];
    const float* dBy = (const float*)d_in[20];
    const float* junif = (const float*)d_in[21];
    const float* sunif = (const float*)d_in[22];
    const float* mcu = (const float*)d_in[23];
    const float* jm  = (const float*)d_in[24];
    const float* cr  = (const float*)d_in[25];
    const float* cfr = (const float*)d_in[26];
    float* ws  = (float*)d_ws;
    float* out = (float*)d_out;

    hipMemsetAsync(ws + OFF_HIST, 0, 220*sizeof(int), stream);
    k_prep<<<4460, 256, 0, stream>>>(rt0, xt0, yt0, dBx, dBy, junif, sunif,
                                     jm, cr, cfr, mcu, W2, Wf2,
                                     W3, b3, emb, Wf3, bf3, jump_r, jump_l,
                                     ws, (int*)(ws + OFF_HIST), out);
    k_fold<<<64, 256, 0, stream>>>((const int*)(ws + OFF_HIST), cr, ws);
    k_mlp<<<2048, 256, 0, stream>>>(ws, W1, b1, Wf1, bf1, b2, bf2,
                                    ws + OFF_CONTRIB);
    k_reduce<<<256, 256, 0, stream>>>(ws + OFF_CONTRIB, u, out);
}